// Round 1
// baseline (189.061 us; speedup 1.0000x reference)
//
#include <hip/hip_runtime.h>

#define EPSV 1e-5f

typedef short bf16x8 __attribute__((ext_vector_type(8)));
typedef float f32x4 __attribute__((ext_vector_type(4)));

static __device__ __forceinline__ unsigned short f2b(float f) {
  union { float f; unsigned u; } v; v.f = f;
  return (unsigned short)((v.u + 0x7fffu + ((v.u >> 16) & 1u)) >> 16);
}

// ---------- kernel A: fused Wfc->bf16 swizzle (blocks 0..511) +
//                      x column partial stats (blocks 512..767) ----------
// wb frag layout: frag id = k32b*16 + nb; lane(quad,l15): n=nb*16+l15,
// k=k32b*32+quad*8; wb[(frag*64+lane)*8 + j] = bf16(Wfc[n][k+j])
// ps1[blk][0:1024)=colsum, [1024:2048)=colsumsq  (256 partial blocks)
__global__ void k_pre(const float* __restrict__ wfc, unsigned short* __restrict__ wb,
                      const float* __restrict__ x, float* __restrict__ ps1) {
  if (blockIdx.x < 512) {
    const int f = blockIdx.x * 256 + threadIdx.x;        // 0..131071
    const int l15 = f & 15, quad = (f >> 4) & 3, nb = (f >> 6) & 15, k32b = f >> 10;
    const int n = nb * 16 + l15;
    const int k = k32b * 32 + quad * 8;
    const float4* src = (const float4*)(wfc + (size_t)n * 4096 + k);
    float4 a = src[0], b = src[1];
    ushort4 o0, o1;
    o0.x = f2b(a.x); o0.y = f2b(a.y); o0.z = f2b(a.z); o0.w = f2b(a.w);
    o1.x = f2b(b.x); o1.y = f2b(b.y); o1.z = f2b(b.z); o1.w = f2b(b.w);
    *(ushort4*)(wb + (size_t)f * 8) = o0;
    *(ushort4*)(wb + (size_t)f * 8 + 4) = o1;
  } else {
    const int blk = blockIdx.x - 512;                    // 0..255
    const int c = threadIdx.x * 4;
    const int r0 = blk * 32;
    float4 s = {0.f,0.f,0.f,0.f}, q = {0.f,0.f,0.f,0.f};
    for (int g = 0; g < 4; ++g) {
      float4 v[8];
#pragma unroll
      for (int j = 0; j < 8; ++j)
        v[j] = *(const float4*)(x + (size_t)(r0 + g*8 + j) * 1024 + c);
#pragma unroll
      for (int j = 0; j < 8; ++j) {
        s.x += v[j].x; s.y += v[j].y; s.z += v[j].z; s.w += v[j].w;
        q.x = fmaf(v[j].x, v[j].x, q.x); q.y = fmaf(v[j].y, v[j].y, q.y);
        q.z = fmaf(v[j].z, v[j].z, q.z); q.w = fmaf(v[j].w, v[j].w, q.w);
      }
    }
    *(float4*)(ps1 + (size_t)blk * 2048 + c) = s;
    *(float4*)(ps1 + (size_t)blk * 2048 + 1024 + c) = q;
  }
}

// ---------- kernel B: reduce 256 partials + finalize BN1 ----
// pt layout [d][56]: j 0..7=s1_i, 8..15=t1_i, 16..47=W2s(o*8+i), 48..51=t2c
// (row-major per d so the gemm can fetch all 52 params in 13 float4 loads)
__global__ __launch_bounds__(256) void k_fin1(const float* __restrict__ ps1,
    const float* __restrict__ W1, const float* __restrict__ g1,
    const float* __restrict__ be1, float* __restrict__ pt) {
  __shared__ float redS[8][32], redQ[8][32];
  const int t = threadIdx.x;
  const int d0 = blockIdx.x * 32;
  const int dl = t & 31, slot = t >> 5;
  float s = 0.f, q = 0.f;
  for (int u = 0; u < 32; u += 8) {
#pragma unroll
    for (int w = 0; w < 8; ++w) {
      const size_t base = (size_t)(slot * 32 + u + w) * 2048 + d0 + dl;
      s += ps1[base];
      q += ps1[base + 1024];
    }
  }
  redS[slot][dl] = s; redQ[slot][dl] = q;
  __syncthreads();
  const int dloc = t >> 3, i = t & 7;                    // 32 d x 8 i
  float xs = 0.f, xq = 0.f;
#pragma unroll
  for (int p = 0; p < 8; ++p) { xs += redS[p][dloc]; xq += redQ[p][dloc]; }
  const float inv = 1.f / 8192.f;
  const int d = d0 + dloc;
  const int c = d * 8 + i;
  float mean = xs * inv;
  float var = xq * inv - mean * mean;
  float w = W1[c];
  float s1 = g1[c] * w * rsqrtf(w * w * var + EPSV);
  float t1 = be1[c] - s1 * mean;
  pt[(size_t)d * 56 + i] = s1;
  pt[(size_t)d * 56 + 8 + i] = t1;
}

// ---------- kernel C: batch partial stats of dot per c2 (no atomics) ----------
__global__ __launch_bounds__(256) void k_stats2(const float* __restrict__ x,
    const float* __restrict__ pt, const float* __restrict__ W2,
    float* __restrict__ ps2s, float* __restrict__ ps2q) {
  __shared__ float red[8][32][8];
  const int t = threadIdx.x;
  const int dl = t & 31, slot = t >> 5;
  const int d = blockIdx.x * 32 + dl;
  float s1v[8], t1v[8], w2v[32];
  {
    const f32x4* pq = (const f32x4*)(pt + (size_t)d * 56);
    f32x4 a = pq[0], b = pq[1], c = pq[2], e = pq[3];
#pragma unroll
    for (int j = 0; j < 4; ++j) {
      s1v[j] = a[j]; s1v[4 + j] = b[j];
      t1v[j] = c[j]; t1v[4 + j] = e[j];
    }
  }
  const float4* wp = (const float4*)(W2 + (size_t)d * 32);
#pragma unroll
  for (int i = 0; i < 8; ++i) {
    float4 v = wp[i];
    w2v[i*4+0]=v.x; w2v[i*4+1]=v.y; w2v[i*4+2]=v.z; w2v[i*4+3]=v.w;
  }
  float s[4] = {0.f,0.f,0.f,0.f}, q[4] = {0.f,0.f,0.f,0.f};
  const int b0 = blockIdx.y * 256 + slot * 32;
  for (int r = 0; r < 32; r += 8) {
    float xv[8];
#pragma unroll
    for (int j = 0; j < 8; ++j)
      xv[j] = x[(size_t)(b0 + r + j) * 1024 + d];
#pragma unroll
    for (int j = 0; j < 8; ++j) {
      float a1[8];
#pragma unroll
      for (int i = 0; i < 8; ++i) a1[i] = fmaxf(fmaf(s1v[i], xv[j], t1v[i]), 0.f);
#pragma unroll
      for (int o = 0; o < 4; ++o) {
        float h = 0.f;
#pragma unroll
        for (int i = 0; i < 8; ++i) h = fmaf(a1[i], w2v[o*8+i], h);
        s[o] += h;
        q[o] = fmaf(h, h, q[o]);
      }
    }
  }
#pragma unroll
  for (int j = 0; j < 4; ++j) {
    red[slot][dl][j] = s[j];
    red[slot][dl][4+j] = q[j];
  }
  __syncthreads();
  const int d2l = t >> 3, j = t & 7;
  float v = 0.f;
#pragma unroll
  for (int p = 0; p < 8; ++p) v += red[p][d2l][j];
  const int c2 = (blockIdx.x * 32 + d2l) * 4 + (t & 3);
  if (j < 4) ps2s[(size_t)blockIdx.y * 4096 + c2] = v;
  else       ps2q[(size_t)blockIdx.y * 4096 + c2] = v;
}

// ---------- kernel D: reduce + finalize BN2 -> pt cols 16..51 ----------
__global__ void k_fin2(const float* __restrict__ W2, const float* __restrict__ g2,
                       const float* __restrict__ be2, const float* __restrict__ ps2s,
                       const float* __restrict__ ps2q, float* __restrict__ pt) {
  const int c2 = blockIdx.x * 256 + threadIdx.x;         // 0..4095
  const int d = c2 >> 2, o = c2 & 3;
  float sm = 0.f, sq = 0.f;
#pragma unroll
  for (int b = 0; b < 32; ++b) {
    sm += ps2s[(size_t)b * 4096 + c2];
    sq += ps2q[(size_t)b * 4096 + c2];
  }
  const float inv = 1.f / 8192.f;
  float m = sm * inv;
  float var = sq * inv - m * m;
  float s2 = g2[c2] * rsqrtf(var + EPSV);
  float t2 = be2[c2] - s2 * m;
  pt[(size_t)d * 56 + 48 + o] = t2;
#pragma unroll
  for (int i = 0; i < 8; ++i)
    pt[(size_t)d * 56 + 16 + o * 8 + i] = W2[(size_t)d * 32 + o * 8 + i] * s2;
}

// ---------- kernel E: fused A-gen + GEMM, v2 ----------
// BM=32, BN=256, chunk=32 d, K-split=4; grid (256,4) x 256 threads
// -> 1024 blocks = 4 blocks/CU. Double-buffered As: one barrier per chunk,
// next chunk's x/pt loads are issued BEFORE the MFMA phase (latency hides
// under MFMA), A-gen of chunk i+1 overlaps other waves' MFMA of chunk i.
__global__ __launch_bounds__(256, 4) void k_gemm(const float* __restrict__ x,
    const float* __restrict__ pt, const unsigned short* __restrict__ wb,
    const float* __restrict__ bfc, float* __restrict__ out) {
  // stride 136 shorts: b128 tile reads are bank-uniform (verified layout)
  __shared__ __align__(16) unsigned short As[2][32 * 136];
  const int t = threadIdx.x;
  const int lane = t & 63;
  const int wv = t >> 6;
  const int m0 = blockIdx.x * 32;
  const int kQ = blockIdx.y;
  const int d0 = kQ * 256;
  const int quad = lane >> 4;
  const int l15 = lane & 15;
  const int dl = t & 31, bs = t >> 5;
  const int chrot = blockIdx.x & 7;

  f32x4 acc[2][4];
#pragma unroll
  for (int mt = 0; mt < 2; ++mt)
#pragma unroll
    for (int nt = 0; nt < 4; ++nt) {
      f32x4 z = {0.f, 0.f, 0.f, 0.f};
      acc[mt][nt] = z;
    }

  float pv[52];
  float xv[4];

#define PREFETCH(CH) do {                                                   \
    const int d_ = d0 + (CH) * 32 + dl;                                     \
    const f32x4* pp_ = (const f32x4*)(pt + (size_t)d_ * 56);                \
    _Pragma("unroll")                                                       \
    for (int i_ = 0; i_ < 13; ++i_) {                                       \
      f32x4 v_ = pp_[i_];                                                   \
      pv[i_*4+0] = v_[0]; pv[i_*4+1] = v_[1];                               \
      pv[i_*4+2] = v_[2]; pv[i_*4+3] = v_[3];                               \
    }                                                                       \
    _Pragma("unroll")                                                       \
    for (int r_ = 0; r_ < 4; ++r_)                                          \
      xv[r_] = x[(size_t)(m0 + bs * 4 + r_) * 1024 + d_];                   \
  } while (0)

#define GEN_TILE(NB) do {                                                   \
    _Pragma("unroll")                                                       \
    for (int r_ = 0; r_ < 4; ++r_) {                                        \
      const float xvv_ = xv[r_];                                            \
      float a1_[8];                                                         \
      _Pragma("unroll")                                                     \
      for (int i_ = 0; i_ < 8; ++i_)                                        \
        a1_[i_] = fmaxf(fmaf(pv[i_], xvv_, pv[8 + i_]), 0.f);               \
      unsigned short o4_[4];                                                \
      _Pragma("unroll")                                                     \
      for (int o_ = 0; o_ < 4; ++o_) {                                      \
        float h_ = pv[48 + o_];                                             \
        _Pragma("unroll")                                                   \
        for (int i_ = 0; i_ < 8; ++i_)                                      \
          h_ = fmaf(a1_[i_], pv[16 + o_ * 8 + i_], h_);                     \
        o4_[o_] = f2b(fmaxf(h_, 0.f));                                      \
      }                                                                     \
      *(ushort4*)&As[NB][(bs * 4 + r_) * 136 + dl * 4] =                    \
          make_ushort4(o4_[0], o4_[1], o4_[2], o4_[3]);                     \
    }                                                                       \
  } while (0)

  // ---- prologue: stage chunk 0 into As[0] ----
  PREFETCH(chrot);
  GEN_TILE(0);
  __syncthreads();

  for (int chi = 0; chi < 8; ++chi) {
    const int cur = chi & 1;
    const int ch = (chi + chrot) & 7;
    // issue next chunk's global loads now; they land during the MFMA phase
    if (chi + 1 < 8) {
      const int chn = (chi + 1 + chrot) & 7;
      PREFETCH(chn);
    }
    // ---- MFMA phase on As[cur]; B loads are contiguous 1KB wave-loads ----
#pragma unroll
    for (int kk = 0; kk < 4; ++kk) {
      bf16x8 af0 = *(const bf16x8*)&As[cur][l15 * 136 + kk * 32 + quad * 8];
      bf16x8 af1 = *(const bf16x8*)&As[cur][(16 + l15) * 136 + kk * 32 + quad * 8];
      const int k32b = kQ * 32 + ch * 4 + kk;
#pragma unroll
      for (int nt = 0; nt < 4; ++nt) {
        const int frag = k32b * 16 + wv * 4 + nt;
        bf16x8 bfr = *(const bf16x8*)&wb[((size_t)frag * 64 + lane) * 8];
        acc[0][nt] = __builtin_amdgcn_mfma_f32_16x16x32_bf16(af0, bfr, acc[0][nt], 0, 0, 0);
        acc[1][nt] = __builtin_amdgcn_mfma_f32_16x16x32_bf16(af1, bfr, acc[1][nt], 0, 0, 0);
      }
    }
    // ---- A-gen of chunk chi+1 into the other buffer (overlaps MFMA of
    //      other waves still in this iteration's MFMA phase) ----
    if (chi + 1 < 8) {
      GEN_TILE(cur ^ 1);
    }
    __syncthreads();
  }

#undef PREFETCH
#undef GEN_TILE

  // ---- epilogue: atomic merge of 4 K-splits; split 0 adds bias ----
#pragma unroll
  for (int nt = 0; nt < 4; ++nt) {
    const int col = wv * 64 + nt * 16 + l15;
    const float bias = (kQ == 0) ? bfc[col] : 0.f;
#pragma unroll
    for (int mt = 0; mt < 2; ++mt) {
#pragma unroll
      for (int r = 0; r < 4; ++r) {
        const int row = m0 + mt * 16 + quad * 4 + r;
        atomicAdd(&out[(size_t)row * 256 + col], acc[mt][nt][r] + bias);
      }
    }
  }
}

extern "C" void kernel_launch(void* const* d_in, const int* in_sizes, int n_in,
                              void* d_out, int out_size, void* d_ws, size_t ws_size,
                              hipStream_t stream) {
  const float* x   = (const float*)d_in[0];
  const float* W1  = (const float*)d_in[1];
  // d_in[2]=b1, d_in[6]=b2 cancel inside the train-mode batchnorms
  const float* g1  = (const float*)d_in[3];
  const float* be1 = (const float*)d_in[4];
  const float* W2  = (const float*)d_in[5];
  const float* g2  = (const float*)d_in[7];
  const float* be2 = (const float*)d_in[8];
  const float* Wfc = (const float*)d_in[9];
  const float* bfc = (const float*)d_in[10];
  float* out = (float*)d_out;

  char* ws = (char*)d_ws;
  unsigned short* wb = (unsigned short*)ws;                 // 2 MB swizzled bf16 Wfc
  float* pt     = (float*)(ws + (2u << 20));                // 229 KB [d][56] params
  float* shared = (float*)(ws + (2u << 20) + (256u << 10)); // 2 MB reused partials
  float* ps1  = shared;                                     // 256 x 2048 (stats1)
  float* ps2s = shared;                                     // 32 x 4096 (stats2 sum)
  float* ps2q = shared + 32 * 4096;                         // 32 x 4096 (stats2 sq)

  hipMemsetAsync(d_out, 0, (size_t)out_size * sizeof(float), stream);

  k_pre   <<<dim3(768),    256, 0, stream>>>(Wfc, wb, x, ps1);
  k_fin1  <<<dim3(32),     256, 0, stream>>>(ps1, W1, g1, be1, pt);
  k_stats2<<<dim3(32, 32), 256, 0, stream>>>(x, pt, W2, ps2s, ps2q);
  k_fin2  <<<dim3(16),     256, 0, stream>>>(W2, g2, be2, ps2s, ps2q, pt);
  k_gemm  <<<dim3(256, 4), 256, 0, stream>>>(x, pt, wb, bfc, out);
}

// Round 2
// 188.516 us; speedup vs baseline: 1.0029x; 1.0029x over previous
//
#include <hip/hip_runtime.h>

#define EPSV 1e-5f

typedef short bf16x8 __attribute__((ext_vector_type(8)));
typedef float f32x4 __attribute__((ext_vector_type(4)));

static __device__ __forceinline__ unsigned short f2b(float f) {
  union { float f; unsigned u; } v; v.f = f;
  return (unsigned short)((v.u + 0x7fffu + ((v.u >> 16) & 1u)) >> 16);
}

// ---------- kernel A: fused Wfc->bf16 swizzle (blocks 0..511) +
//                      x column partial stats (blocks 512..767) ----------
// wb frag layout: frag id = k32b*16 + nb; lane(quad,l15): n=nb*16+l15,
// k=k32b*32+quad*8; wb[(frag*64+lane)*8 + j] = bf16(Wfc[n][k+j])
// ps1[blk][0:1024)=colsum, [1024:2048)=colsumsq  (256 partial blocks)
__global__ void k_pre(const float* __restrict__ wfc, unsigned short* __restrict__ wb,
                      const float* __restrict__ x, float* __restrict__ ps1) {
  if (blockIdx.x < 512) {
    const int f = blockIdx.x * 256 + threadIdx.x;        // 0..131071
    const int l15 = f & 15, quad = (f >> 4) & 3, nb = (f >> 6) & 15, k32b = f >> 10;
    const int n = nb * 16 + l15;
    const int k = k32b * 32 + quad * 8;
    const float4* src = (const float4*)(wfc + (size_t)n * 4096 + k);
    float4 a = src[0], b = src[1];
    ushort4 o0, o1;
    o0.x = f2b(a.x); o0.y = f2b(a.y); o0.z = f2b(a.z); o0.w = f2b(a.w);
    o1.x = f2b(b.x); o1.y = f2b(b.y); o1.z = f2b(b.z); o1.w = f2b(b.w);
    *(ushort4*)(wb + (size_t)f * 8) = o0;
    *(ushort4*)(wb + (size_t)f * 8 + 4) = o1;
  } else {
    const int blk = blockIdx.x - 512;                    // 0..255
    const int c = threadIdx.x * 4;
    const int r0 = blk * 32;
    float4 s = {0.f,0.f,0.f,0.f}, q = {0.f,0.f,0.f,0.f};
    for (int g = 0; g < 4; ++g) {
      float4 v[8];
#pragma unroll
      for (int j = 0; j < 8; ++j)
        v[j] = *(const float4*)(x + (size_t)(r0 + g*8 + j) * 1024 + c);
#pragma unroll
      for (int j = 0; j < 8; ++j) {
        s.x += v[j].x; s.y += v[j].y; s.z += v[j].z; s.w += v[j].w;
        q.x = fmaf(v[j].x, v[j].x, q.x); q.y = fmaf(v[j].y, v[j].y, q.y);
        q.z = fmaf(v[j].z, v[j].z, q.z); q.w = fmaf(v[j].w, v[j].w, q.w);
      }
    }
    *(float4*)(ps1 + (size_t)blk * 2048 + c) = s;
    *(float4*)(ps1 + (size_t)blk * 2048 + 1024 + c) = q;
  }
}

// ---------- kernel B: reduce 256 partials + finalize BN1 ----
// pt layout [d][56]: j 0..7=s1_i, 8..15=t1_i, 16..47=W2s(o*8+i), 48..51=t2c
// (row-major per d so the gemm can fetch all 52 params in 13 float4 loads)
__global__ __launch_bounds__(256) void k_fin1(const float* __restrict__ ps1,
    const float* __restrict__ W1, const float* __restrict__ g1,
    const float* __restrict__ be1, float* __restrict__ pt) {
  __shared__ float redS[8][32], redQ[8][32];
  const int t = threadIdx.x;
  const int d0 = blockIdx.x * 32;
  const int dl = t & 31, slot = t >> 5;
  float s = 0.f, q = 0.f;
  for (int u = 0; u < 32; u += 8) {
#pragma unroll
    for (int w = 0; w < 8; ++w) {
      const size_t base = (size_t)(slot * 32 + u + w) * 2048 + d0 + dl;
      s += ps1[base];
      q += ps1[base + 1024];
    }
  }
  redS[slot][dl] = s; redQ[slot][dl] = q;
  __syncthreads();
  const int dloc = t >> 3, i = t & 7;                    // 32 d x 8 i
  float xs = 0.f, xq = 0.f;
#pragma unroll
  for (int p = 0; p < 8; ++p) { xs += redS[p][dloc]; xq += redQ[p][dloc]; }
  const float inv = 1.f / 8192.f;
  const int d = d0 + dloc;
  const int c = d * 8 + i;
  float mean = xs * inv;
  float var = xq * inv - mean * mean;
  float w = W1[c];
  float s1 = g1[c] * w * rsqrtf(w * w * var + EPSV);
  float t1 = be1[c] - s1 * mean;
  pt[(size_t)d * 56 + i] = s1;
  pt[(size_t)d * 56 + 8 + i] = t1;
}

// ---------- kernel C: batch partial stats of dot per c2 (no atomics) ----------
__global__ __launch_bounds__(256) void k_stats2(const float* __restrict__ x,
    const float* __restrict__ pt, const float* __restrict__ W2,
    float* __restrict__ ps2s, float* __restrict__ ps2q) {
  __shared__ float red[8][32][8];
  const int t = threadIdx.x;
  const int dl = t & 31, slot = t >> 5;
  const int d = blockIdx.x * 32 + dl;
  float s1v[8], t1v[8], w2v[32];
  {
    const f32x4* pq = (const f32x4*)(pt + (size_t)d * 56);
    f32x4 a = pq[0], b = pq[1], c = pq[2], e = pq[3];
#pragma unroll
    for (int j = 0; j < 4; ++j) {
      s1v[j] = a[j]; s1v[4 + j] = b[j];
      t1v[j] = c[j]; t1v[4 + j] = e[j];
    }
  }
  const float4* wp = (const float4*)(W2 + (size_t)d * 32);
#pragma unroll
  for (int i = 0; i < 8; ++i) {
    float4 v = wp[i];
    w2v[i*4+0]=v.x; w2v[i*4+1]=v.y; w2v[i*4+2]=v.z; w2v[i*4+3]=v.w;
  }
  float s[4] = {0.f,0.f,0.f,0.f}, q[4] = {0.f,0.f,0.f,0.f};
  const int b0 = blockIdx.y * 256 + slot * 32;
  for (int r = 0; r < 32; r += 8) {
    float xv[8];
#pragma unroll
    for (int j = 0; j < 8; ++j)
      xv[j] = x[(size_t)(b0 + r + j) * 1024 + d];
#pragma unroll
    for (int j = 0; j < 8; ++j) {
      float a1[8];
#pragma unroll
      for (int i = 0; i < 8; ++i) a1[i] = fmaxf(fmaf(s1v[i], xv[j], t1v[i]), 0.f);
#pragma unroll
      for (int o = 0; o < 4; ++o) {
        float h = 0.f;
#pragma unroll
        for (int i = 0; i < 8; ++i) h = fmaf(a1[i], w2v[o*8+i], h);
        s[o] += h;
        q[o] = fmaf(h, h, q[o]);
      }
    }
  }
#pragma unroll
  for (int j = 0; j < 4; ++j) {
    red[slot][dl][j] = s[j];
    red[slot][dl][4+j] = q[j];
  }
  __syncthreads();
  const int d2l = t >> 3, j = t & 7;
  float v = 0.f;
#pragma unroll
  for (int p = 0; p < 8; ++p) v += red[p][d2l][j];
  const int c2 = (blockIdx.x * 32 + d2l) * 4 + (t & 3);
  if (j < 4) ps2s[(size_t)blockIdx.y * 4096 + c2] = v;
  else       ps2q[(size_t)blockIdx.y * 4096 + c2] = v;
}

// ---------- kernel D: reduce + finalize BN2 -> pt cols 16..51 ----------
__global__ void k_fin2(const float* __restrict__ W2, const float* __restrict__ g2,
                       const float* __restrict__ be2, const float* __restrict__ ps2s,
                       const float* __restrict__ ps2q, float* __restrict__ pt) {
  const int c2 = blockIdx.x * 256 + threadIdx.x;         // 0..4095
  const int d = c2 >> 2, o = c2 & 3;
  float sm = 0.f, sq = 0.f;
#pragma unroll
  for (int b = 0; b < 32; ++b) {
    sm += ps2s[(size_t)b * 4096 + c2];
    sq += ps2q[(size_t)b * 4096 + c2];
  }
  const float inv = 1.f / 8192.f;
  float m = sm * inv;
  float var = sq * inv - m * m;
  float s2 = g2[c2] * rsqrtf(var + EPSV);
  float t2 = be2[c2] - s2 * m;
  pt[(size_t)d * 56 + 48 + o] = t2;
#pragma unroll
  for (int i = 0; i < 8; ++i)
    pt[(size_t)d * 56 + 16 + o * 8 + i] = W2[(size_t)d * 32 + o * 8 + i] * s2;
}

// ---------- kernel E: fused A-gen + GEMM, v3 ----------
// BM=32, BN=256, chunk=32 d, K-split=4; grid (256,4) x 256 threads.
// Double-buffered As, one barrier per chunk, next chunk's x/pt loads issued
// before the MFMA phase. launch_bounds(256,3): VGPR budget 170 so pv[52]
// stays in registers (the (256,4) variant capped at 128 and SPILLED pv to
// scratch: VGPR_Count=64, FETCH +4MB, dur +7us — measured round 1).
__global__ __launch_bounds__(256, 3) void k_gemm(const float* __restrict__ x,
    const float* __restrict__ pt, const unsigned short* __restrict__ wb,
    const float* __restrict__ bfc, float* __restrict__ out) {
  // stride 136 shorts: b128 tile reads are bank-uniform (verified layout)
  __shared__ __align__(16) unsigned short As[2][32 * 136];
  const int t = threadIdx.x;
  const int lane = t & 63;
  const int wv = t >> 6;
  const int m0 = blockIdx.x * 32;
  const int kQ = blockIdx.y;
  const int d0 = kQ * 256;
  const int quad = lane >> 4;
  const int l15 = lane & 15;
  const int dl = t & 31, bs = t >> 5;
  const int chrot = blockIdx.x & 7;

  f32x4 acc[2][4];
#pragma unroll
  for (int mt = 0; mt < 2; ++mt)
#pragma unroll
    for (int nt = 0; nt < 4; ++nt) {
      f32x4 z = {0.f, 0.f, 0.f, 0.f};
      acc[mt][nt] = z;
    }

  float pv[52];
  float xv[4];

#define PREFETCH(CH) do {                                                   \
    const int d_ = d0 + (CH) * 32 + dl;                                     \
    const f32x4* pp_ = (const f32x4*)(pt + (size_t)d_ * 56);                \
    _Pragma("unroll")                                                       \
    for (int i_ = 0; i_ < 13; ++i_) {                                       \
      f32x4 v_ = pp_[i_];                                                   \
      pv[i_*4+0] = v_[0]; pv[i_*4+1] = v_[1];                               \
      pv[i_*4+2] = v_[2]; pv[i_*4+3] = v_[3];                               \
    }                                                                       \
    _Pragma("unroll")                                                       \
    for (int r_ = 0; r_ < 4; ++r_)                                          \
      xv[r_] = x[(size_t)(m0 + bs * 4 + r_) * 1024 + d_];                   \
  } while (0)

#define GEN_TILE(NB) do {                                                   \
    _Pragma("unroll")                                                       \
    for (int r_ = 0; r_ < 4; ++r_) {                                        \
      const float xvv_ = xv[r_];                                            \
      float a1_[8];                                                         \
      _Pragma("unroll")                                                     \
      for (int i_ = 0; i_ < 8; ++i_)                                        \
        a1_[i_] = fmaxf(fmaf(pv[i_], xvv_, pv[8 + i_]), 0.f);               \
      unsigned short o4_[4];                                                \
      _Pragma("unroll")                                                     \
      for (int o_ = 0; o_ < 4; ++o_) {                                      \
        float h_ = pv[48 + o_];                                             \
        _Pragma("unroll")                                                   \
        for (int i_ = 0; i_ < 8; ++i_)                                      \
          h_ = fmaf(a1_[i_], pv[16 + o_ * 8 + i_], h_);                     \
        o4_[o_] = f2b(fmaxf(h_, 0.f));                                      \
      }                                                                     \
      *(ushort4*)&As[NB][(bs * 4 + r_) * 136 + dl * 4] =                    \
          make_ushort4(o4_[0], o4_[1], o4_[2], o4_[3]);                     \
    }                                                                       \
  } while (0)

  // ---- prologue: stage chunk 0 into As[0] ----
  PREFETCH(chrot);
  GEN_TILE(0);
  __syncthreads();

  for (int chi = 0; chi < 8; ++chi) {
    const int cur = chi & 1;
    const int ch = (chi + chrot) & 7;
    // issue next chunk's global loads now; they land during the MFMA phase
    if (chi + 1 < 8) {
      const int chn = (chi + 1 + chrot) & 7;
      PREFETCH(chn);
    }
    // ---- MFMA phase on As[cur]; B loads are contiguous 1KB wave-loads ----
#pragma unroll
    for (int kk = 0; kk < 4; ++kk) {
      bf16x8 af0 = *(const bf16x8*)&As[cur][l15 * 136 + kk * 32 + quad * 8];
      bf16x8 af1 = *(const bf16x8*)&As[cur][(16 + l15) * 136 + kk * 32 + quad * 8];
      const int k32b = kQ * 32 + ch * 4 + kk;
#pragma unroll
      for (int nt = 0; nt < 4; ++nt) {
        const int frag = k32b * 16 + wv * 4 + nt;
        bf16x8 bfr = *(const bf16x8*)&wb[((size_t)frag * 64 + lane) * 8];
        acc[0][nt] = __builtin_amdgcn_mfma_f32_16x16x32_bf16(af0, bfr, acc[0][nt], 0, 0, 0);
        acc[1][nt] = __builtin_amdgcn_mfma_f32_16x16x32_bf16(af1, bfr, acc[1][nt], 0, 0, 0);
      }
    }
    // ---- A-gen of chunk chi+1 into the other buffer (overlaps MFMA of
    //      other waves still in this iteration's MFMA phase) ----
    if (chi + 1 < 8) {
      GEN_TILE(cur ^ 1);
    }
    __syncthreads();
  }

#undef PREFETCH
#undef GEN_TILE

  // ---- epilogue: atomic merge of 4 K-splits; split 0 adds bias ----
#pragma unroll
  for (int nt = 0; nt < 4; ++nt) {
    const int col = wv * 64 + nt * 16 + l15;
    const float bias = (kQ == 0) ? bfc[col] : 0.f;
#pragma unroll
    for (int mt = 0; mt < 2; ++mt) {
#pragma unroll
      for (int r = 0; r < 4; ++r) {
        const int row = m0 + mt * 16 + quad * 4 + r;
        atomicAdd(&out[(size_t)row * 256 + col], acc[mt][nt][r] + bias);
      }
    }
  }
}

extern "C" void kernel_launch(void* const* d_in, const int* in_sizes, int n_in,
                              void* d_out, int out_size, void* d_ws, size_t ws_size,
                              hipStream_t stream) {
  const float* x   = (const float*)d_in[0];
  const float* W1  = (const float*)d_in[1];
  // d_in[2]=b1, d_in[6]=b2 cancel inside the train-mode batchnorms
  const float* g1  = (const float*)d_in[3];
  const float* be1 = (const float*)d_in[4];
  const float* W2  = (const float*)d_in[5];
  const float* g2  = (const float*)d_in[7];
  const float* be2 = (const float*)d_in[8];
  const float* Wfc = (const float*)d_in[9];
  const float* bfc = (const float*)d_in[10];
  float* out = (float*)d_out;

  char* ws = (char*)d_ws;
  unsigned short* wb = (unsigned short*)ws;                 // 2 MB swizzled bf16 Wfc
  float* pt     = (float*)(ws + (2u << 20));                // 229 KB [d][56] params
  float* shared = (float*)(ws + (2u << 20) + (256u << 10)); // 2 MB reused partials
  float* ps1  = shared;                                     // 256 x 2048 (stats1)
  float* ps2s = shared;                                     // 32 x 4096 (stats2 sum)
  float* ps2q = shared + 32 * 4096;                         // 32 x 4096 (stats2 sq)

  hipMemsetAsync(d_out, 0, (size_t)out_size * sizeof(float), stream);

  k_pre   <<<dim3(768),    256, 0, stream>>>(Wfc, wb, x, ps1);
  k_fin1  <<<dim3(32),     256, 0, stream>>>(ps1, W1, g1, be1, pt);
  k_stats2<<<dim3(32, 32), 256, 0, stream>>>(x, pt, W2, ps2s, ps2q);
  k_fin2  <<<dim3(16),     256, 0, stream>>>(W2, g2, be2, ps2s, ps2q, pt);
  k_gemm  <<<dim3(256, 4), 256, 0, stream>>>(x, pt, wb, bfc, out);
}

// Round 3
// 181.659 us; speedup vs baseline: 1.0407x; 1.0377x over previous
//
#include <hip/hip_runtime.h>

#define EPSV 1e-5f

typedef short bf16x8 __attribute__((ext_vector_type(8)));
typedef float f32x4 __attribute__((ext_vector_type(4)));
typedef const __attribute__((address_space(1))) unsigned int gu32;
typedef __attribute__((address_space(3))) unsigned int lu32;

static __device__ __forceinline__ unsigned short f2b(float f) {
  union { float f; unsigned u; } v; v.f = f;
  return (unsigned short)((v.u + 0x7fffu + ((v.u >> 16) & 1u)) >> 16);
}

// ---------- kernel A: fused Wfc->bf16 swizzle (blocks 0..511) +
//                      x column partial stats (blocks 512..767) ----------
// wb frag layout: frag id = k32b*16 + nb; lane(quad,l15): n=nb*16+l15,
// k=k32b*32+quad*8; wb[(frag*64+lane)*8 + j] = bf16(Wfc[n][k+j])
// ps1[blk][0:1024)=colsum, [1024:2048)=colsumsq  (256 partial blocks)
__global__ void k_pre(const float* __restrict__ wfc, unsigned short* __restrict__ wb,
                      const float* __restrict__ x, float* __restrict__ ps1) {
  if (blockIdx.x < 512) {
    const int f = blockIdx.x * 256 + threadIdx.x;        // 0..131071
    const int l15 = f & 15, quad = (f >> 4) & 3, nb = (f >> 6) & 15, k32b = f >> 10;
    const int n = nb * 16 + l15;
    const int k = k32b * 32 + quad * 8;
    const float4* src = (const float4*)(wfc + (size_t)n * 4096 + k);
    float4 a = src[0], b = src[1];
    ushort4 o0, o1;
    o0.x = f2b(a.x); o0.y = f2b(a.y); o0.z = f2b(a.z); o0.w = f2b(a.w);
    o1.x = f2b(b.x); o1.y = f2b(b.y); o1.z = f2b(b.z); o1.w = f2b(b.w);
    *(ushort4*)(wb + (size_t)f * 8) = o0;
    *(ushort4*)(wb + (size_t)f * 8 + 4) = o1;
  } else {
    const int blk = blockIdx.x - 512;                    // 0..255
    const int c = threadIdx.x * 4;
    const int r0 = blk * 32;
    float4 s = {0.f,0.f,0.f,0.f}, q = {0.f,0.f,0.f,0.f};
    for (int g = 0; g < 4; ++g) {
      float4 v[8];
#pragma unroll
      for (int j = 0; j < 8; ++j)
        v[j] = *(const float4*)(x + (size_t)(r0 + g*8 + j) * 1024 + c);
#pragma unroll
      for (int j = 0; j < 8; ++j) {
        s.x += v[j].x; s.y += v[j].y; s.z += v[j].z; s.w += v[j].w;
        q.x = fmaf(v[j].x, v[j].x, q.x); q.y = fmaf(v[j].y, v[j].y, q.y);
        q.z = fmaf(v[j].z, v[j].z, q.z); q.w = fmaf(v[j].w, v[j].w, q.w);
      }
    }
    *(float4*)(ps1 + (size_t)blk * 2048 + c) = s;
    *(float4*)(ps1 + (size_t)blk * 2048 + 1024 + c) = q;
  }
}

// ---------- kernel B: reduce 256 partials + finalize BN1 ----
// pt layout [d][56]: j 0..7=s1_i, 8..15=t1_i, 16..47=W2s(o*8+i), 48..51=t2c
__global__ __launch_bounds__(256) void k_fin1(const float* __restrict__ ps1,
    const float* __restrict__ W1, const float* __restrict__ g1,
    const float* __restrict__ be1, float* __restrict__ pt) {
  __shared__ float redS[8][32], redQ[8][32];
  const int t = threadIdx.x;
  const int d0 = blockIdx.x * 32;
  const int dl = t & 31, slot = t >> 5;
  float s = 0.f, q = 0.f;
  for (int u = 0; u < 32; u += 8) {
#pragma unroll
    for (int w = 0; w < 8; ++w) {
      const size_t base = (size_t)(slot * 32 + u + w) * 2048 + d0 + dl;
      s += ps1[base];
      q += ps1[base + 1024];
    }
  }
  redS[slot][dl] = s; redQ[slot][dl] = q;
  __syncthreads();
  const int dloc = t >> 3, i = t & 7;                    // 32 d x 8 i
  float xs = 0.f, xq = 0.f;
#pragma unroll
  for (int p = 0; p < 8; ++p) { xs += redS[p][dloc]; xq += redQ[p][dloc]; }
  const float inv = 1.f / 8192.f;
  const int d = d0 + dloc;
  const int c = d * 8 + i;
  float mean = xs * inv;
  float var = xq * inv - mean * mean;
  float w = W1[c];
  float s1 = g1[c] * w * rsqrtf(w * w * var + EPSV);
  float t1 = be1[c] - s1 * mean;
  pt[(size_t)d * 56 + i] = s1;
  pt[(size_t)d * 56 + 8 + i] = t1;
}

// ---------- kernel C: batch partial stats of dot per c2 (no atomics) ----------
__global__ __launch_bounds__(256) void k_stats2(const float* __restrict__ x,
    const float* __restrict__ pt, const float* __restrict__ W2,
    float* __restrict__ ps2s, float* __restrict__ ps2q) {
  __shared__ float red[8][32][8];
  const int t = threadIdx.x;
  const int dl = t & 31, slot = t >> 5;
  const int d = blockIdx.x * 32 + dl;
  float s1v[8], t1v[8], w2v[32];
  {
    const f32x4* pq = (const f32x4*)(pt + (size_t)d * 56);
    f32x4 a = pq[0], b = pq[1], c = pq[2], e = pq[3];
#pragma unroll
    for (int j = 0; j < 4; ++j) {
      s1v[j] = a[j]; s1v[4 + j] = b[j];
      t1v[j] = c[j]; t1v[4 + j] = e[j];
    }
  }
  const float4* wp = (const float4*)(W2 + (size_t)d * 32);
#pragma unroll
  for (int i = 0; i < 8; ++i) {
    float4 v = wp[i];
    w2v[i*4+0]=v.x; w2v[i*4+1]=v.y; w2v[i*4+2]=v.z; w2v[i*4+3]=v.w;
  }
  float s[4] = {0.f,0.f,0.f,0.f}, q[4] = {0.f,0.f,0.f,0.f};
  const int b0 = blockIdx.y * 256 + slot * 32;
  for (int r = 0; r < 32; r += 8) {
    float xv[8];
#pragma unroll
    for (int j = 0; j < 8; ++j)
      xv[j] = x[(size_t)(b0 + r + j) * 1024 + d];
#pragma unroll
    for (int j = 0; j < 8; ++j) {
      float a1[8];
#pragma unroll
      for (int i = 0; i < 8; ++i) a1[i] = fmaxf(fmaf(s1v[i], xv[j], t1v[i]), 0.f);
#pragma unroll
      for (int o = 0; o < 4; ++o) {
        float h = 0.f;
#pragma unroll
        for (int i = 0; i < 8; ++i) h = fmaf(a1[i], w2v[o*8+i], h);
        s[o] += h;
        q[o] = fmaf(h, h, q[o]);
      }
    }
  }
#pragma unroll
  for (int j = 0; j < 4; ++j) {
    red[slot][dl][j] = s[j];
    red[slot][dl][4+j] = q[j];
  }
  __syncthreads();
  const int d2l = t >> 3, j = t & 7;
  float v = 0.f;
#pragma unroll
  for (int p = 0; p < 8; ++p) v += red[p][d2l][j];
  const int c2 = (blockIdx.x * 32 + d2l) * 4 + (t & 3);
  if (j < 4) ps2s[(size_t)blockIdx.y * 4096 + c2] = v;
  else       ps2q[(size_t)blockIdx.y * 4096 + c2] = v;
}

// ---------- kernel D: reduce + finalize BN2 -> pt cols 16..51 ----------
__global__ void k_fin2(const float* __restrict__ W2, const float* __restrict__ g2,
                       const float* __restrict__ be2, const float* __restrict__ ps2s,
                       const float* __restrict__ ps2q, float* __restrict__ pt) {
  const int c2 = blockIdx.x * 256 + threadIdx.x;         // 0..4095
  const int d = c2 >> 2, o = c2 & 3;
  float sm = 0.f, sq = 0.f;
#pragma unroll
  for (int b = 0; b < 32; ++b) {
    sm += ps2s[(size_t)b * 4096 + c2];
    sq += ps2q[(size_t)b * 4096 + c2];
  }
  const float inv = 1.f / 8192.f;
  float m = sm * inv;
  float var = sq * inv - m * m;
  float s2 = g2[c2] * rsqrtf(var + EPSV);
  float t2 = be2[c2] - s2 * m;
  pt[(size_t)d * 56 + 48 + o] = t2;
#pragma unroll
  for (int i = 0; i < 8; ++i)
    pt[(size_t)d * 56 + 16 + o * 8 + i] = W2[(size_t)d * 32 + o * 8 + i] * s2;
}

// ---------- kernel E: fused A-gen + GEMM, v4 ----------
// BM=64, BN=256, chunk=16 d (K=64 bf16), K-split=4; grid (128,4) x 256 thr.
// B staged into LDS double-buffer via global_load_lds (zero-VGPR DMA):
// MFMA phase reads ONLY LDS; staging of chunk i+1 overlaps gen of chunk i+1
// and drains at the barrier before its MFMA. This removes the L2-latency
// serialization on wb loads that dominated rounds 0-2 (~45us of stall:
// MfmaUtil*dur == ideal MFMA time, rest was waitcnt).
__global__ __launch_bounds__(256, 2) void k_gemm(const float* __restrict__ x,
    const float* __restrict__ pt, const unsigned short* __restrict__ wb,
    const float* __restrict__ bfc, float* __restrict__ out) {
  // Bs: 32 frags x 64 lanes x 8 shorts = 32KB per buffer; lane-contiguous
  // 16B reads -> conflict-free b128. As: stride 72 shorts (144B: 16B-aligned
  // rows, 2-way bank alias = free).
  __shared__ __align__(16) unsigned short Bs[2][32 * 512];
  __shared__ __align__(16) unsigned short As[64 * 72];
  const int t = threadIdx.x;
  const int lane = t & 63;
  const int wv = t >> 6;
  const int m0 = blockIdx.x * 64;
  const int kQ = blockIdx.y;
  const int quad = lane >> 4;
  const int l15 = lane & 15;
  const int dloc = t & 15, rowg = t >> 4;   // gen map: 16 d x 16 rowgroups x 4 rows
  const int k32q = kQ * 32;                 // base k32b of this K-split

  f32x4 acc[4][4];
#pragma unroll
  for (int mt = 0; mt < 4; ++mt)
#pragma unroll
    for (int nt = 0; nt < 4; ++nt) {
      f32x4 z = {0.f, 0.f, 0.f, 0.f};
      acc[mt][nt] = z;
    }

  float xv[4];

  // async-stage chunk CH's 32 B-frags into Bs[BUF]; 8 issues/wave, no VGPR dst
#define STAGE_B(CH, BUF) do {                                               \
    const int k32b0_ = k32q + (CH) * 2;                                     \
    _Pragma("unroll")                                                       \
    for (int j_ = 0; j_ < 8; ++j_) {                                        \
      const int fl_ = j_ * 4 + wv;                                          \
      const int gfrag_ = (k32b0_ + (fl_ >> 4)) * 16 + (fl_ & 15);           \
      const unsigned short* gp_ = wb + ((size_t)gfrag_ * 64 + lane) * 8;    \
      __builtin_amdgcn_global_load_lds((gu32*)gp_,                          \
          (lu32*)&Bs[BUF][fl_ * 512], 16, 0, 0);                            \
    }                                                                       \
  } while (0)

#define PRE_X(CH) do {                                                      \
    const int d_ = kQ * 256 + (CH) * 16 + dloc;                             \
    _Pragma("unroll")                                                       \
    for (int r_ = 0; r_ < 4; ++r_)                                          \
      xv[r_] = x[(size_t)(m0 + rowg * 4 + r_) * 1024 + d_];                 \
  } while (0)

  // gen chunk CH: params JIT from L2 (live only inside this phase)
#define GEN_A(CH) do {                                                      \
    const int d_ = kQ * 256 + (CH) * 16 + dloc;                             \
    const f32x4* pp_ = (const f32x4*)(pt + (size_t)d_ * 56);                \
    float pv_[52];                                                          \
    _Pragma("unroll")                                                       \
    for (int i_ = 0; i_ < 13; ++i_) {                                       \
      f32x4 v_ = pp_[i_];                                                   \
      pv_[i_*4+0] = v_[0]; pv_[i_*4+1] = v_[1];                             \
      pv_[i_*4+2] = v_[2]; pv_[i_*4+3] = v_[3];                             \
    }                                                                       \
    _Pragma("unroll")                                                       \
    for (int r_ = 0; r_ < 4; ++r_) {                                        \
      const float xvv_ = xv[r_];                                            \
      float a1_[8];                                                         \
      _Pragma("unroll")                                                     \
      for (int i_ = 0; i_ < 8; ++i_)                                        \
        a1_[i_] = fmaxf(fmaf(pv_[i_], xvv_, pv_[8 + i_]), 0.f);             \
      unsigned short o4_[4];                                                \
      _Pragma("unroll")                                                     \
      for (int o_ = 0; o_ < 4; ++o_) {                                      \
        float h_ = pv_[48 + o_];                                            \
        _Pragma("unroll")                                                   \
        for (int i_ = 0; i_ < 8; ++i_)                                      \
          h_ = fmaf(a1_[i_], pv_[16 + o_ * 8 + i_], h_);                    \
        o4_[o_] = f2b(fmaxf(h_, 0.f));                                      \
      }                                                                     \
      *(ushort4*)&As[(rowg * 4 + r_) * 72 + dloc * 4] =                     \
          make_ushort4(o4_[0], o4_[1], o4_[2], o4_[3]);                     \
    }                                                                       \
  } while (0)

  // ---- prologue: stage B(0) + gen A(0) ----
  STAGE_B(0, 0);
  PRE_X(0);
  GEN_A(0);
  __syncthreads();   // As + Bs[0] ready (barrier drains the DMA)

  for (int chi = 0; chi < 16; ++chi) {
    const int cur = chi & 1;
    if (chi < 15) PRE_X(chi + 1);          // 4 regs, lands during MFMA
    // ---- MFMA phase: LDS-only reads ----
#pragma unroll
    for (int kk = 0; kk < 2; ++kk) {
      bf16x8 af[4];
#pragma unroll
      for (int mt = 0; mt < 4; ++mt)
        af[mt] = *(const bf16x8*)&As[(mt * 16 + l15) * 72 + kk * 32 + quad * 8];
#pragma unroll
      for (int nt = 0; nt < 4; ++nt) {
        const int fl = kk * 16 + wv * 4 + nt;
        bf16x8 bfr = *(const bf16x8*)&Bs[cur][fl * 512 + lane * 8];
#pragma unroll
        for (int mt = 0; mt < 4; ++mt)
          acc[mt][nt] = __builtin_amdgcn_mfma_f32_16x16x32_bf16(af[mt], bfr,
                                                                acc[mt][nt], 0, 0, 0);
      }
    }
    __syncthreads();   // all waves done reading As + Bs[cur]
    if (chi < 15) {
      STAGE_B(chi + 1, cur ^ 1);  // DMA overlaps gen below; drains at next bar
      GEN_A(chi + 1);             // writes As (safe: post-barrier)
    }
    __syncthreads();
  }

#undef STAGE_B
#undef PRE_X
#undef GEN_A

  // ---- epilogue: atomic merge of 4 K-splits; split 0 adds bias ----
#pragma unroll
  for (int nt = 0; nt < 4; ++nt) {
    const int col = wv * 64 + nt * 16 + l15;
    const float bias = (kQ == 0) ? bfc[col] : 0.f;
#pragma unroll
    for (int mt = 0; mt < 4; ++mt) {
#pragma unroll
      for (int r = 0; r < 4; ++r) {
        const int row = m0 + mt * 16 + quad * 4 + r;
        atomicAdd(&out[(size_t)row * 256 + col], acc[mt][nt][r] + bias);
      }
    }
  }
}

extern "C" void kernel_launch(void* const* d_in, const int* in_sizes, int n_in,
                              void* d_out, int out_size, void* d_ws, size_t ws_size,
                              hipStream_t stream) {
  const float* x   = (const float*)d_in[0];
  const float* W1  = (const float*)d_in[1];
  // d_in[2]=b1, d_in[6]=b2 cancel inside the train-mode batchnorms
  const float* g1  = (const float*)d_in[3];
  const float* be1 = (const float*)d_in[4];
  const float* W2  = (const float*)d_in[5];
  const float* g2  = (const float*)d_in[7];
  const float* be2 = (const float*)d_in[8];
  const float* Wfc = (const float*)d_in[9];
  const float* bfc = (const float*)d_in[10];
  float* out = (float*)d_out;

  char* ws = (char*)d_ws;
  unsigned short* wb = (unsigned short*)ws;                 // 2 MB swizzled bf16 Wfc
  float* pt     = (float*)(ws + (2u << 20));                // 229 KB [d][56] params
  float* shared = (float*)(ws + (2u << 20) + (256u << 10)); // 2 MB reused partials
  float* ps1  = shared;                                     // 256 x 2048 (stats1)
  float* ps2s = shared;                                     // 32 x 4096 (stats2 sum)
  float* ps2q = shared + 32 * 4096;                         // 32 x 4096 (stats2 sq)

  hipMemsetAsync(d_out, 0, (size_t)out_size * sizeof(float), stream);

  k_pre   <<<dim3(768),    256, 0, stream>>>(Wfc, wb, x, ps1);
  k_fin1  <<<dim3(32),     256, 0, stream>>>(ps1, W1, g1, be1, pt);
  k_stats2<<<dim3(32, 32), 256, 0, stream>>>(x, pt, W2, ps2s, ps2q);
  k_fin2  <<<dim3(16),     256, 0, stream>>>(W2, g2, be2, ps2s, ps2q, pt);
  k_gemm  <<<dim3(128, 4), 256, 0, stream>>>(x, pt, wb, bfc, out);
}

// Round 4
// 173.627 us; speedup vs baseline: 1.0889x; 1.0463x over previous
//
#include <hip/hip_runtime.h>

#define EPSV 1e-5f

typedef short bf16x8 __attribute__((ext_vector_type(8)));
typedef float f32x4 __attribute__((ext_vector_type(4)));
typedef const __attribute__((address_space(1))) unsigned int gu32;
typedef __attribute__((address_space(3))) unsigned int lu32;

static __device__ __forceinline__ unsigned short f2b(float f) {
  union { float f; unsigned u; } v; v.f = f;
  return (unsigned short)((v.u + 0x7fffu + ((v.u >> 16) & 1u)) >> 16);
}

// ---------- kernel A: fused Wfc->bf16 swizzle (blocks 0..511) +
//                      x column partial stats (blocks 512..767) ----------
// wb frag layout: frag id = k32b*16 + nb; lane(quad,l15): n=nb*16+l15,
// k=k32b*32+quad*8; wb[(frag*64+lane)*8 + j] = bf16(Wfc[n][k+j])
// ps1[blk][0:1024)=colsum, [1024:2048)=colsumsq  (256 partial blocks)
__global__ void k_pre(const float* __restrict__ wfc, unsigned short* __restrict__ wb,
                      const float* __restrict__ x, float* __restrict__ ps1) {
  if (blockIdx.x < 512) {
    const int f = blockIdx.x * 256 + threadIdx.x;        // 0..131071
    const int l15 = f & 15, quad = (f >> 4) & 3, nb = (f >> 6) & 15, k32b = f >> 10;
    const int n = nb * 16 + l15;
    const int k = k32b * 32 + quad * 8;
    const float4* src = (const float4*)(wfc + (size_t)n * 4096 + k);
    float4 a = src[0], b = src[1];
    ushort4 o0, o1;
    o0.x = f2b(a.x); o0.y = f2b(a.y); o0.z = f2b(a.z); o0.w = f2b(a.w);
    o1.x = f2b(b.x); o1.y = f2b(b.y); o1.z = f2b(b.z); o1.w = f2b(b.w);
    *(ushort4*)(wb + (size_t)f * 8) = o0;
    *(ushort4*)(wb + (size_t)f * 8 + 4) = o1;
  } else {
    const int blk = blockIdx.x - 512;                    // 0..255
    const int c = threadIdx.x * 4;
    const int r0 = blk * 32;
    float4 s = {0.f,0.f,0.f,0.f}, q = {0.f,0.f,0.f,0.f};
    for (int g = 0; g < 4; ++g) {
      float4 v[8];
#pragma unroll
      for (int j = 0; j < 8; ++j)
        v[j] = *(const float4*)(x + (size_t)(r0 + g*8 + j) * 1024 + c);
#pragma unroll
      for (int j = 0; j < 8; ++j) {
        s.x += v[j].x; s.y += v[j].y; s.z += v[j].z; s.w += v[j].w;
        q.x = fmaf(v[j].x, v[j].x, q.x); q.y = fmaf(v[j].y, v[j].y, q.y);
        q.z = fmaf(v[j].z, v[j].z, q.z); q.w = fmaf(v[j].w, v[j].w, q.w);
      }
    }
    *(float4*)(ps1 + (size_t)blk * 2048 + c) = s;
    *(float4*)(ps1 + (size_t)blk * 2048 + 1024 + c) = q;
  }
}

// ---------- kernel B: reduce 256 partials + finalize BN1 ----
// pt layout [d][56]: j 0..7=s1_i, 8..15=t1_i, 16..47=W2s(o*8+i), 48..51=t2c
__global__ __launch_bounds__(256) void k_fin1(const float* __restrict__ ps1,
    const float* __restrict__ W1, const float* __restrict__ g1,
    const float* __restrict__ be1, float* __restrict__ pt) {
  __shared__ float redS[8][32], redQ[8][32];
  const int t = threadIdx.x;
  const int d0 = blockIdx.x * 32;
  const int dl = t & 31, slot = t >> 5;
  float s = 0.f, q = 0.f;
  for (int u = 0; u < 32; u += 8) {
#pragma unroll
    for (int w = 0; w < 8; ++w) {
      const size_t base = (size_t)(slot * 32 + u + w) * 2048 + d0 + dl;
      s += ps1[base];
      q += ps1[base + 1024];
    }
  }
  redS[slot][dl] = s; redQ[slot][dl] = q;
  __syncthreads();
  const int dloc = t >> 3, i = t & 7;                    // 32 d x 8 i
  float xs = 0.f, xq = 0.f;
#pragma unroll
  for (int p = 0; p < 8; ++p) { xs += redS[p][dloc]; xq += redQ[p][dloc]; }
  const float inv = 1.f / 8192.f;
  const int d = d0 + dloc;
  const int c = d * 8 + i;
  float mean = xs * inv;
  float var = xq * inv - mean * mean;
  float w = W1[c];
  float s1 = g1[c] * w * rsqrtf(w * w * var + EPSV);
  float t1 = be1[c] - s1 * mean;
  pt[(size_t)d * 56 + i] = s1;
  pt[(size_t)d * 56 + 8 + i] = t1;
}

// ---------- kernel C: batch partial stats of dot per c2 (no atomics) ----------
__global__ __launch_bounds__(256) void k_stats2(const float* __restrict__ x,
    const float* __restrict__ pt, const float* __restrict__ W2,
    float* __restrict__ ps2s, float* __restrict__ ps2q) {
  __shared__ float red[8][32][8];
  const int t = threadIdx.x;
  const int dl = t & 31, slot = t >> 5;
  const int d = blockIdx.x * 32 + dl;
  float s1v[8], t1v[8], w2v[32];
  {
    const f32x4* pq = (const f32x4*)(pt + (size_t)d * 56);
    f32x4 a = pq[0], b = pq[1], c = pq[2], e = pq[3];
#pragma unroll
    for (int j = 0; j < 4; ++j) {
      s1v[j] = a[j]; s1v[4 + j] = b[j];
      t1v[j] = c[j]; t1v[4 + j] = e[j];
    }
  }
  const float4* wp = (const float4*)(W2 + (size_t)d * 32);
#pragma unroll
  for (int i = 0; i < 8; ++i) {
    float4 v = wp[i];
    w2v[i*4+0]=v.x; w2v[i*4+1]=v.y; w2v[i*4+2]=v.z; w2v[i*4+3]=v.w;
  }
  float s[4] = {0.f,0.f,0.f,0.f}, q[4] = {0.f,0.f,0.f,0.f};
  const int b0 = blockIdx.y * 256 + slot * 32;
  for (int r = 0; r < 32; r += 8) {
    float xv[8];
#pragma unroll
    for (int j = 0; j < 8; ++j)
      xv[j] = x[(size_t)(b0 + r + j) * 1024 + d];
#pragma unroll
    for (int j = 0; j < 8; ++j) {
      float a1[8];
#pragma unroll
      for (int i = 0; i < 8; ++i) a1[i] = fmaxf(fmaf(s1v[i], xv[j], t1v[i]), 0.f);
#pragma unroll
      for (int o = 0; o < 4; ++o) {
        float h = 0.f;
#pragma unroll
        for (int i = 0; i < 8; ++i) h = fmaf(a1[i], w2v[o*8+i], h);
        s[o] += h;
        q[o] = fmaf(h, h, q[o]);
      }
    }
  }
#pragma unroll
  for (int j = 0; j < 4; ++j) {
    red[slot][dl][j] = s[j];
    red[slot][dl][4+j] = q[j];
  }
  __syncthreads();
  const int d2l = t >> 3, j = t & 7;
  float v = 0.f;
#pragma unroll
  for (int p = 0; p < 8; ++p) v += red[p][d2l][j];
  const int c2 = (blockIdx.x * 32 + d2l) * 4 + (t & 3);
  if (j < 4) ps2s[(size_t)blockIdx.y * 4096 + c2] = v;
  else       ps2q[(size_t)blockIdx.y * 4096 + c2] = v;
}

// ---------- kernel D: reduce + finalize BN2 -> pt cols 16..51 ----------
__global__ void k_fin2(const float* __restrict__ W2, const float* __restrict__ g2,
                       const float* __restrict__ be2, const float* __restrict__ ps2s,
                       const float* __restrict__ ps2q, float* __restrict__ pt) {
  const int c2 = blockIdx.x * 256 + threadIdx.x;         // 0..4095
  const int d = c2 >> 2, o = c2 & 3;
  float sm = 0.f, sq = 0.f;
#pragma unroll
  for (int b = 0; b < 32; ++b) {
    sm += ps2s[(size_t)b * 4096 + c2];
    sq += ps2q[(size_t)b * 4096 + c2];
  }
  const float inv = 1.f / 8192.f;
  float m = sm * inv;
  float var = sq * inv - m * m;
  float s2 = g2[c2] * rsqrtf(var + EPSV);
  float t2 = be2[c2] - s2 * m;
  pt[(size_t)d * 56 + 48 + o] = t2;
#pragma unroll
  for (int i = 0; i < 8; ++i)
    pt[(size_t)d * 56 + 16 + o * 8 + i] = W2[(size_t)d * 32 + o * 8 + i] * s2;
}

// ---------- kernel E: fused A-gen + GEMM, v5 ----------
// Main loop identical to v4 (LDS-staged B via global_load_lds, double-buffer).
// EPILOGUE EXPERIMENT: rounds 0-3 all ~66-73us regardless of main-loop
// structure; WRITE_SIZE=33.5MB == 8.4M atomics x 4B -> every atomicAdd is a
// memory-side RMW (est 25-40us). use_part=1: each kQ block stores its f32
// accumulators to a private 8MB slab (plain coalesced stores), k_merge sums
// the 4 slabs + bias (L3-resident, ~6us). Fallback (small ws): old atomics.
__global__ __launch_bounds__(256, 2) void k_gemm(const float* __restrict__ x,
    const float* __restrict__ pt, const unsigned short* __restrict__ wb,
    const float* __restrict__ bfc, float* __restrict__ out,
    float* __restrict__ part, const int use_part) {
  __shared__ __align__(16) unsigned short Bs[2][32 * 512];
  __shared__ __align__(16) unsigned short As[64 * 72];
  const int t = threadIdx.x;
  const int lane = t & 63;
  const int wv = t >> 6;
  const int m0 = blockIdx.x * 64;
  const int kQ = blockIdx.y;
  const int quad = lane >> 4;
  const int l15 = lane & 15;
  const int dloc = t & 15, rowg = t >> 4;   // gen map: 16 d x 16 rowgroups x 4 rows
  const int k32q = kQ * 32;                 // base k32b of this K-split

  f32x4 acc[4][4];
#pragma unroll
  for (int mt = 0; mt < 4; ++mt)
#pragma unroll
    for (int nt = 0; nt < 4; ++nt) {
      f32x4 z = {0.f, 0.f, 0.f, 0.f};
      acc[mt][nt] = z;
    }

  float xv[4];

  // async-stage chunk CH's 32 B-frags into Bs[BUF]; 8 issues/wave, no VGPR dst
#define STAGE_B(CH, BUF) do {                                               \
    const int k32b0_ = k32q + (CH) * 2;                                     \
    _Pragma("unroll")                                                       \
    for (int j_ = 0; j_ < 8; ++j_) {                                        \
      const int fl_ = j_ * 4 + wv;                                          \
      const int gfrag_ = (k32b0_ + (fl_ >> 4)) * 16 + (fl_ & 15);           \
      const unsigned short* gp_ = wb + ((size_t)gfrag_ * 64 + lane) * 8;    \
      __builtin_amdgcn_global_load_lds((gu32*)gp_,                          \
          (lu32*)&Bs[BUF][fl_ * 512], 16, 0, 0);                            \
    }                                                                       \
  } while (0)

#define PRE_X(CH) do {                                                      \
    const int d_ = kQ * 256 + (CH) * 16 + dloc;                             \
    _Pragma("unroll")                                                       \
    for (int r_ = 0; r_ < 4; ++r_)                                          \
      xv[r_] = x[(size_t)(m0 + rowg * 4 + r_) * 1024 + d_];                 \
  } while (0)

  // gen chunk CH: params JIT from L2 (live only inside this phase)
#define GEN_A(CH) do {                                                      \
    const int d_ = kQ * 256 + (CH) * 16 + dloc;                             \
    const f32x4* pp_ = (const f32x4*)(pt + (size_t)d_ * 56);                \
    float pv_[52];                                                          \
    _Pragma("unroll")                                                       \
    for (int i_ = 0; i_ < 13; ++i_) {                                       \
      f32x4 v_ = pp_[i_];                                                   \
      pv_[i_*4+0] = v_[0]; pv_[i_*4+1] = v_[1];                             \
      pv_[i_*4+2] = v_[2]; pv_[i_*4+3] = v_[3];                             \
    }                                                                       \
    _Pragma("unroll")                                                       \
    for (int r_ = 0; r_ < 4; ++r_) {                                        \
      const float xvv_ = xv[r_];                                            \
      float a1_[8];                                                         \
      _Pragma("unroll")                                                     \
      for (int i_ = 0; i_ < 8; ++i_)                                        \
        a1_[i_] = fmaxf(fmaf(pv_[i_], xvv_, pv_[8 + i_]), 0.f);             \
      unsigned short o4_[4];                                                \
      _Pragma("unroll")                                                     \
      for (int o_ = 0; o_ < 4; ++o_) {                                      \
        float h_ = pv_[48 + o_];                                            \
        _Pragma("unroll")                                                   \
        for (int i_ = 0; i_ < 8; ++i_)                                      \
          h_ = fmaf(a1_[i_], pv_[16 + o_ * 8 + i_], h_);                    \
        o4_[o_] = f2b(fmaxf(h_, 0.f));                                      \
      }                                                                     \
      *(ushort4*)&As[(rowg * 4 + r_) * 72 + dloc * 4] =                     \
          make_ushort4(o4_[0], o4_[1], o4_[2], o4_[3]);                     \
    }                                                                       \
  } while (0)

  // ---- prologue: stage B(0) + gen A(0) ----
  STAGE_B(0, 0);
  PRE_X(0);
  GEN_A(0);
  __syncthreads();   // As + Bs[0] ready (barrier drains the DMA)

  for (int chi = 0; chi < 16; ++chi) {
    const int cur = chi & 1;
    if (chi < 15) PRE_X(chi + 1);          // 4 regs, lands during MFMA
    // ---- MFMA phase: LDS-only reads ----
#pragma unroll
    for (int kk = 0; kk < 2; ++kk) {
      bf16x8 af[4];
#pragma unroll
      for (int mt = 0; mt < 4; ++mt)
        af[mt] = *(const bf16x8*)&As[(mt * 16 + l15) * 72 + kk * 32 + quad * 8];
#pragma unroll
      for (int nt = 0; nt < 4; ++nt) {
        const int fl = kk * 16 + wv * 4 + nt;
        bf16x8 bfr = *(const bf16x8*)&Bs[cur][fl * 512 + lane * 8];
#pragma unroll
        for (int mt = 0; mt < 4; ++mt)
          acc[mt][nt] = __builtin_amdgcn_mfma_f32_16x16x32_bf16(af[mt], bfr,
                                                                acc[mt][nt], 0, 0, 0);
      }
    }
    __syncthreads();   // all waves done reading As + Bs[cur]
    if (chi < 15) {
      STAGE_B(chi + 1, cur ^ 1);  // DMA overlaps gen below; drains at next bar
      GEN_A(chi + 1);             // writes As (safe: post-barrier)
    }
    __syncthreads();
  }

#undef STAGE_B
#undef PRE_X
#undef GEN_A

  if (use_part) {
    // ---- plain coalesced stores to this kQ's private partial slab ----
    float* dst = part + (size_t)kQ * (8192 * 256);
#pragma unroll
    for (int nt = 0; nt < 4; ++nt) {
      const int col = wv * 64 + nt * 16 + l15;
#pragma unroll
      for (int mt = 0; mt < 4; ++mt) {
#pragma unroll
        for (int r = 0; r < 4; ++r) {
          const int row = m0 + mt * 16 + quad * 4 + r;
          dst[(size_t)row * 256 + col] = acc[mt][nt][r];
        }
      }
    }
  } else {
    // ---- fallback: atomic merge of 4 K-splits; split 0 adds bias ----
#pragma unroll
    for (int nt = 0; nt < 4; ++nt) {
      const int col = wv * 64 + nt * 16 + l15;
      const float bias = (kQ == 0) ? bfc[col] : 0.f;
#pragma unroll
      for (int mt = 0; mt < 4; ++mt) {
#pragma unroll
        for (int r = 0; r < 4; ++r) {
          const int row = m0 + mt * 16 + quad * 4 + r;
          atomicAdd(&out[(size_t)row * 256 + col], acc[mt][nt][r] + bias);
        }
      }
    }
  }
}

// ---------- kernel F: merge 4 partial slabs + bias ----------
// 524288 float4 elements; grid 2048 x 256 -> one float4/thread.
__global__ void k_merge(const float* __restrict__ part, const float* __restrict__ bfc,
                        float* __restrict__ out) {
  const size_t i = (size_t)blockIdx.x * 256 + threadIdx.x;
  const size_t SL = (size_t)8192 * 256;
  f32x4 a = ((const f32x4*)part)[i];
  f32x4 b = ((const f32x4*)(part + SL))[i];
  f32x4 c = ((const f32x4*)(part + 2 * SL))[i];
  f32x4 d = ((const f32x4*)(part + 3 * SL))[i];
  const int col = (int)((i * 4) & 255);
  f32x4 bv = *(const f32x4*)(bfc + col);
  ((f32x4*)out)[i] = a + b + c + d + bv;
}

extern "C" void kernel_launch(void* const* d_in, const int* in_sizes, int n_in,
                              void* d_out, int out_size, void* d_ws, size_t ws_size,
                              hipStream_t stream) {
  const float* x   = (const float*)d_in[0];
  const float* W1  = (const float*)d_in[1];
  // d_in[2]=b1, d_in[6]=b2 cancel inside the train-mode batchnorms
  const float* g1  = (const float*)d_in[3];
  const float* be1 = (const float*)d_in[4];
  const float* W2  = (const float*)d_in[5];
  const float* g2  = (const float*)d_in[7];
  const float* be2 = (const float*)d_in[8];
  const float* Wfc = (const float*)d_in[9];
  const float* bfc = (const float*)d_in[10];
  float* out = (float*)d_out;

  char* ws = (char*)d_ws;
  unsigned short* wb = (unsigned short*)ws;                 // 2 MB swizzled bf16 Wfc
  float* pt     = (float*)(ws + (2u << 20));                // 229 KB [d][56] params
  float* shared = (float*)(ws + (2u << 20) + (256u << 10)); // 2 MB reused partials
  float* ps1  = shared;                                     // 256 x 2048 (stats1)
  float* ps2s = shared;                                     // 32 x 4096 (stats2 sum)
  float* ps2q = shared + 32 * 4096;                         // 32 x 4096 (stats2 sq)

  const size_t PART_OFF = (2u << 20) + (256u << 10) + (2u << 20);  // 4,456,448
  const size_t PART_SZ  = (size_t)4 * 8192 * 256 * sizeof(float);  // 32 MB
  float* part = (float*)(ws + PART_OFF);
  const int use_part = (ws_size >= PART_OFF + PART_SZ) ? 1 : 0;

  if (!use_part)
    hipMemsetAsync(d_out, 0, (size_t)out_size * sizeof(float), stream);

  k_pre   <<<dim3(768),    256, 0, stream>>>(Wfc, wb, x, ps1);
  k_fin1  <<<dim3(32),     256, 0, stream>>>(ps1, W1, g1, be1, pt);
  k_stats2<<<dim3(32, 32), 256, 0, stream>>>(x, pt, W2, ps2s, ps2q);
  k_fin2  <<<dim3(16),     256, 0, stream>>>(W2, g2, be2, ps2s, ps2q, pt);
  k_gemm  <<<dim3(128, 4), 256, 0, stream>>>(x, pt, wb, bfc, out, part, use_part);
  if (use_part)
    k_merge<<<dim3(2048),  256, 0, stream>>>(part, bfc, out);
}

// Round 5
// 161.230 us; speedup vs baseline: 1.1726x; 1.0769x over previous
//
#include <hip/hip_runtime.h>

#define EPSV 1e-5f

typedef short bf16x8 __attribute__((ext_vector_type(8)));
typedef float f32x4 __attribute__((ext_vector_type(4)));
typedef const __attribute__((address_space(1))) unsigned int gu32;
typedef __attribute__((address_space(3))) unsigned int lu32;

static __device__ __forceinline__ unsigned short f2b(float f) {
  union { float f; unsigned u; } v; v.f = f;
  return (unsigned short)((v.u + 0x7fffu + ((v.u >> 16) & 1u)) >> 16);
}

// ---------- kernel A: fused Wfc->bf16 swizzle (blocks 0..511) +
//                      x column partial stats (blocks 512..767) ----------
// wb frag layout: frag id = k32b*16 + nb; lane(quad,l15): n=nb*16+l15,
// k=k32b*32+quad*8; wb[(frag*64+lane)*8 + j] = bf16(Wfc[n][k+j])
// ps1[blk][0:1024)=colsum, [1024:2048)=colsumsq  (256 partial blocks)
__global__ void k_pre(const float* __restrict__ wfc, unsigned short* __restrict__ wb,
                      const float* __restrict__ x, float* __restrict__ ps1) {
  if (blockIdx.x < 512) {
    const int f = blockIdx.x * 256 + threadIdx.x;        // 0..131071
    const int l15 = f & 15, quad = (f >> 4) & 3, nb = (f >> 6) & 15, k32b = f >> 10;
    const int n = nb * 16 + l15;
    const int k = k32b * 32 + quad * 8;
    const float4* src = (const float4*)(wfc + (size_t)n * 4096 + k);
    float4 a = src[0], b = src[1];
    ushort4 o0, o1;
    o0.x = f2b(a.x); o0.y = f2b(a.y); o0.z = f2b(a.z); o0.w = f2b(a.w);
    o1.x = f2b(b.x); o1.y = f2b(b.y); o1.z = f2b(b.z); o1.w = f2b(b.w);
    *(ushort4*)(wb + (size_t)f * 8) = o0;
    *(ushort4*)(wb + (size_t)f * 8 + 4) = o1;
  } else {
    const int blk = blockIdx.x - 512;                    // 0..255
    const int c = threadIdx.x * 4;
    const int r0 = blk * 32;
    float4 s = {0.f,0.f,0.f,0.f}, q = {0.f,0.f,0.f,0.f};
    for (int g = 0; g < 4; ++g) {
      float4 v[8];
#pragma unroll
      for (int j = 0; j < 8; ++j)
        v[j] = *(const float4*)(x + (size_t)(r0 + g*8 + j) * 1024 + c);
#pragma unroll
      for (int j = 0; j < 8; ++j) {
        s.x += v[j].x; s.y += v[j].y; s.z += v[j].z; s.w += v[j].w;
        q.x = fmaf(v[j].x, v[j].x, q.x); q.y = fmaf(v[j].y, v[j].y, q.y);
        q.z = fmaf(v[j].z, v[j].z, q.z); q.w = fmaf(v[j].w, v[j].w, q.w);
      }
    }
    *(float4*)(ps1 + (size_t)blk * 2048 + c) = s;
    *(float4*)(ps1 + (size_t)blk * 2048 + 1024 + c) = q;
  }
}

// ---------- kernel B: reduce 256 partials + finalize BN1 ----
// pt layout [d][52] (PACKED so a 16-d chunk is one contiguous 3328B block
// for global_load_lds): j 0..7=s1_i, 8..15=t1_i, 16..47=W2s(o*8+i), 48..51=t2c
__global__ __launch_bounds__(256) void k_fin1(const float* __restrict__ ps1,
    const float* __restrict__ W1, const float* __restrict__ g1,
    const float* __restrict__ be1, float* __restrict__ pt) {
  __shared__ float redS[8][32], redQ[8][32];
  const int t = threadIdx.x;
  const int d0 = blockIdx.x * 32;
  const int dl = t & 31, slot = t >> 5;
  float s = 0.f, q = 0.f;
  for (int u = 0; u < 32; u += 8) {
#pragma unroll
    for (int w = 0; w < 8; ++w) {
      const size_t base = (size_t)(slot * 32 + u + w) * 2048 + d0 + dl;
      s += ps1[base];
      q += ps1[base + 1024];
    }
  }
  redS[slot][dl] = s; redQ[slot][dl] = q;
  __syncthreads();
  const int dloc = t >> 3, i = t & 7;                    // 32 d x 8 i
  float xs = 0.f, xq = 0.f;
#pragma unroll
  for (int p = 0; p < 8; ++p) { xs += redS[p][dloc]; xq += redQ[p][dloc]; }
  const float inv = 1.f / 8192.f;
  const int d = d0 + dloc;
  const int c = d * 8 + i;
  float mean = xs * inv;
  float var = xq * inv - mean * mean;
  float w = W1[c];
  float s1 = g1[c] * w * rsqrtf(w * w * var + EPSV);
  float t1 = be1[c] - s1 * mean;
  pt[(size_t)d * 52 + i] = s1;
  pt[(size_t)d * 52 + 8 + i] = t1;
}

// ---------- kernel C: batch partial stats of dot per c2 (no atomics) ----------
__global__ __launch_bounds__(256) void k_stats2(const float* __restrict__ x,
    const float* __restrict__ pt, const float* __restrict__ W2,
    float* __restrict__ ps2s, float* __restrict__ ps2q) {
  __shared__ float red[8][32][8];
  const int t = threadIdx.x;
  const int dl = t & 31, slot = t >> 5;
  const int d = blockIdx.x * 32 + dl;
  float s1v[8], t1v[8], w2v[32];
  {
    const f32x4* pq = (const f32x4*)(pt + (size_t)d * 52);
    f32x4 a = pq[0], b = pq[1], c = pq[2], e = pq[3];
#pragma unroll
    for (int j = 0; j < 4; ++j) {
      s1v[j] = a[j]; s1v[4 + j] = b[j];
      t1v[j] = c[j]; t1v[4 + j] = e[j];
    }
  }
  const float4* wp = (const float4*)(W2 + (size_t)d * 32);
#pragma unroll
  for (int i = 0; i < 8; ++i) {
    float4 v = wp[i];
    w2v[i*4+0]=v.x; w2v[i*4+1]=v.y; w2v[i*4+2]=v.z; w2v[i*4+3]=v.w;
  }
  float s[4] = {0.f,0.f,0.f,0.f}, q[4] = {0.f,0.f,0.f,0.f};
  const int b0 = blockIdx.y * 256 + slot * 32;
  for (int r = 0; r < 32; r += 8) {
    float xv[8];
#pragma unroll
    for (int j = 0; j < 8; ++j)
      xv[j] = x[(size_t)(b0 + r + j) * 1024 + d];
#pragma unroll
    for (int j = 0; j < 8; ++j) {
      float a1[8];
#pragma unroll
      for (int i = 0; i < 8; ++i) a1[i] = fmaxf(fmaf(s1v[i], xv[j], t1v[i]), 0.f);
#pragma unroll
      for (int o = 0; o < 4; ++o) {
        float h = 0.f;
#pragma unroll
        for (int i = 0; i < 8; ++i) h = fmaf(a1[i], w2v[o*8+i], h);
        s[o] += h;
        q[o] = fmaf(h, h, q[o]);
      }
    }
  }
#pragma unroll
  for (int j = 0; j < 4; ++j) {
    red[slot][dl][j] = s[j];
    red[slot][dl][4+j] = q[j];
  }
  __syncthreads();
  const int d2l = t >> 3, j = t & 7;
  float v = 0.f;
#pragma unroll
  for (int p = 0; p < 8; ++p) v += red[p][d2l][j];
  const int c2 = (blockIdx.x * 32 + d2l) * 4 + (t & 3);
  if (j < 4) ps2s[(size_t)blockIdx.y * 4096 + c2] = v;
  else       ps2q[(size_t)blockIdx.y * 4096 + c2] = v;
}

// ---------- kernel D: reduce + finalize BN2 -> pt cols 16..51 ----------
__global__ void k_fin2(const float* __restrict__ W2, const float* __restrict__ g2,
                       const float* __restrict__ be2, const float* __restrict__ ps2s,
                       const float* __restrict__ ps2q, float* __restrict__ pt) {
  const int c2 = blockIdx.x * 256 + threadIdx.x;         // 0..4095
  const int d = c2 >> 2, o = c2 & 3;
  float sm = 0.f, sq = 0.f;
#pragma unroll
  for (int b = 0; b < 32; ++b) {
    sm += ps2s[(size_t)b * 4096 + c2];
    sq += ps2q[(size_t)b * 4096 + c2];
  }
  const float inv = 1.f / 8192.f;
  float m = sm * inv;
  float var = sq * inv - m * m;
  float s2 = g2[c2] * rsqrtf(var + EPSV);
  float t2 = be2[c2] - s2 * m;
  pt[(size_t)d * 52 + 48 + o] = t2;
#pragma unroll
  for (int i = 0; i < 8; ++i)
    pt[(size_t)d * 52 + 16 + o * 8 + i] = W2[(size_t)d * 32 + o * 8 + i] * s2;
}

// ---------- kernel E: fused A-gen + GEMM, v6 ----------
// v5 + chunk params staged in LDS. Round-4 diagnosis: GEN_A's per-thread
// 13x f32x4 pt loads = 435MB of 208B-strided L2 reads (each wave-load
// splinters into ~64 cacheline transactions) -- the dominant stall.
// Fix: one global_load_lds DMA per chunk (3328B contiguous, threads 0..207
// x 16B) into Ps; GEN reads params from LDS (4-way broadcast + 2-way bank
// alias = free). Single Ps buffer is race-free: staged in phase A (last
// reader GEN(chi) retired before preceding bar2), drained by bar1, read in
// phase B. Param traffic 435MB scattered -> 27MB coalesced.
__global__ __launch_bounds__(256, 2) void k_gemm(const float* __restrict__ x,
    const float* __restrict__ pt, const unsigned short* __restrict__ wb,
    const float* __restrict__ bfc, float* __restrict__ out,
    float* __restrict__ part, const int use_part) {
  __shared__ __align__(16) unsigned short Bs[2][32 * 512];
  __shared__ __align__(16) unsigned short As[64 * 72];
  __shared__ __align__(16) float Ps[16 * 52];   // chunk params [dloc][52]
  const int t = threadIdx.x;
  const int lane = t & 63;
  const int wv = t >> 6;
  const int m0 = blockIdx.x * 64;
  const int kQ = blockIdx.y;
  const int quad = lane >> 4;
  const int l15 = lane & 15;
  const int dloc = t & 15, rowg = t >> 4;   // gen map: 16 d x 16 rowgroups x 4 rows
  const int k32q = kQ * 32;                 // base k32b of this K-split

  f32x4 acc[4][4];
#pragma unroll
  for (int mt = 0; mt < 4; ++mt)
#pragma unroll
    for (int nt = 0; nt < 4; ++nt) {
      f32x4 z = {0.f, 0.f, 0.f, 0.f};
      acc[mt][nt] = z;
    }

  float xv[4];

  // async-stage chunk CH's 32 B-frags into Bs[BUF]; 8 issues/wave, no VGPR dst
#define STAGE_B(CH, BUF) do {                                               \
    const int k32b0_ = k32q + (CH) * 2;                                     \
    _Pragma("unroll")                                                       \
    for (int j_ = 0; j_ < 8; ++j_) {                                        \
      const int fl_ = j_ * 4 + wv;                                          \
      const int gfrag_ = (k32b0_ + (fl_ >> 4)) * 16 + (fl_ & 15);           \
      const unsigned short* gp_ = wb + ((size_t)gfrag_ * 64 + lane) * 8;    \
      __builtin_amdgcn_global_load_lds((gu32*)gp_,                          \
          (lu32*)&Bs[BUF][fl_ * 512], 16, 0, 0);                            \
    }                                                                       \
  } while (0)

  // async-stage chunk CH's 16x52 params (3328B contiguous) into Ps
#define STAGE_P(CH) do {                                                    \
    if (t < 208) {                                                          \
      const float* gp_ = pt + (size_t)(kQ * 256 + (CH) * 16) * 52 + t * 4;  \
      __builtin_amdgcn_global_load_lds((gu32*)gp_,                          \
          (lu32*)&Ps[t * 4], 16, 0, 0);                                     \
    }                                                                       \
  } while (0)

#define PRE_X(CH) do {                                                      \
    const int d_ = kQ * 256 + (CH) * 16 + dloc;                             \
    _Pragma("unroll")                                                       \
    for (int r_ = 0; r_ < 4; ++r_)                                          \
      xv[r_] = x[(size_t)(m0 + rowg * 4 + r_) * 1024 + d_];                 \
  } while (0)

  // gen chunk CH: params from Ps (LDS); identical arithmetic to v5
#define GEN_A() do {                                                        \
    const f32x4* pq_ = (const f32x4*)&Ps[dloc * 52];                        \
    float pv_[52];                                                          \
    _Pragma("unroll")                                                       \
    for (int i_ = 0; i_ < 13; ++i_) {                                       \
      f32x4 v_ = pq_[i_];                                                   \
      pv_[i_*4+0] = v_[0]; pv_[i_*4+1] = v_[1];                             \
      pv_[i_*4+2] = v_[2]; pv_[i_*4+3] = v_[3];                             \
    }                                                                       \
    _Pragma("unroll")                                                       \
    for (int r_ = 0; r_ < 4; ++r_) {                                        \
      const float xvv_ = xv[r_];                                            \
      float a1_[8];                                                         \
      _Pragma("unroll")                                                     \
      for (int i_ = 0; i_ < 8; ++i_)                                        \
        a1_[i_] = fmaxf(fmaf(pv_[i_], xvv_, pv_[8 + i_]), 0.f);             \
      unsigned short o4_[4];                                                \
      _Pragma("unroll")                                                     \
      for (int o_ = 0; o_ < 4; ++o_) {                                      \
        float h_ = pv_[48 + o_];                                            \
        _Pragma("unroll")                                                   \
        for (int i_ = 0; i_ < 8; ++i_)                                      \
          h_ = fmaf(a1_[i_], pv_[16 + o_ * 8 + i_], h_);                    \
        o4_[o_] = f2b(fmaxf(h_, 0.f));                                      \
      }                                                                     \
      *(ushort4*)&As[(rowg * 4 + r_) * 72 + dloc * 4] =                     \
          make_ushort4(o4_[0], o4_[1], o4_[2], o4_[3]);                     \
    }                                                                       \
  } while (0)

  // ---- prologue: stage P(0)+B(0), gen A(0) ----
  STAGE_P(0);
  STAGE_B(0, 0);
  PRE_X(0);
  __syncthreads();   // drains both DMAs; Ps+Bs[0] ready
  GEN_A();
  __syncthreads();   // As(0) ready

  for (int chi = 0; chi < 16; ++chi) {
    const int cur = chi & 1;
    if (chi < 15) {
      PRE_X(chi + 1);        // 4 regs, lands during MFMA
      STAGE_P(chi + 1);      // DMA -> Ps; safe (GEN(chi) retired at bar2);
    }                        // drains at bar1 below
    // ---- MFMA phase: LDS-only reads ----
#pragma unroll
    for (int kk = 0; kk < 2; ++kk) {
      bf16x8 af[4];
#pragma unroll
      for (int mt = 0; mt < 4; ++mt)
        af[mt] = *(const bf16x8*)&As[(mt * 16 + l15) * 72 + kk * 32 + quad * 8];
#pragma unroll
      for (int nt = 0; nt < 4; ++nt) {
        const int fl = kk * 16 + wv * 4 + nt;
        bf16x8 bfr = *(const bf16x8*)&Bs[cur][fl * 512 + lane * 8];
#pragma unroll
        for (int mt = 0; mt < 4; ++mt)
          acc[mt][nt] = __builtin_amdgcn_mfma_f32_16x16x32_bf16(af[mt], bfr,
                                                                acc[mt][nt], 0, 0, 0);
      }
    }
    __syncthreads();   // bar1: waves done reading As+Bs[cur]; Ps DMA drained
    if (chi < 15) {
      STAGE_B(chi + 1, cur ^ 1);  // DMA overlaps gen; drains at bar2
      GEN_A();                    // reads Ps, writes As
    }
    __syncthreads();   // bar2
  }

#undef STAGE_B
#undef STAGE_P
#undef PRE_X
#undef GEN_A

  if (use_part) {
    // ---- plain coalesced stores to this kQ's private partial slab ----
    float* dst = part + (size_t)kQ * (8192 * 256);
#pragma unroll
    for (int nt = 0; nt < 4; ++nt) {
      const int col = wv * 64 + nt * 16 + l15;
#pragma unroll
      for (int mt = 0; mt < 4; ++mt) {
#pragma unroll
        for (int r = 0; r < 4; ++r) {
          const int row = m0 + mt * 16 + quad * 4 + r;
          dst[(size_t)row * 256 + col] = acc[mt][nt][r];
        }
      }
    }
  } else {
    // ---- fallback: atomic merge of 4 K-splits; split 0 adds bias ----
#pragma unroll
    for (int nt = 0; nt < 4; ++nt) {
      const int col = wv * 64 + nt * 16 + l15;
      const float bias = (kQ == 0) ? bfc[col] : 0.f;
#pragma unroll
      for (int mt = 0; mt < 4; ++mt) {
#pragma unroll
        for (int r = 0; r < 4; ++r) {
          const int row = m0 + mt * 16 + quad * 4 + r;
          atomicAdd(&out[(size_t)row * 256 + col], acc[mt][nt][r] + bias);
        }
      }
    }
  }
}

// ---------- kernel F: merge 4 partial slabs + bias ----------
// 524288 float4 elements; grid 2048 x 256 -> one float4/thread.
__global__ void k_merge(const float* __restrict__ part, const float* __restrict__ bfc,
                        float* __restrict__ out) {
  const size_t i = (size_t)blockIdx.x * 256 + threadIdx.x;
  const size_t SL = (size_t)8192 * 256;
  f32x4 a = ((const f32x4*)part)[i];
  f32x4 b = ((const f32x4*)(part + SL))[i];
  f32x4 c = ((const f32x4*)(part + 2 * SL))[i];
  f32x4 d = ((const f32x4*)(part + 3 * SL))[i];
  const int col = (int)((i * 4) & 255);
  f32x4 bv = *(const f32x4*)(bfc + col);
  ((f32x4*)out)[i] = a + b + c + d + bv;
}

extern "C" void kernel_launch(void* const* d_in, const int* in_sizes, int n_in,
                              void* d_out, int out_size, void* d_ws, size_t ws_size,
                              hipStream_t stream) {
  const float* x   = (const float*)d_in[0];
  const float* W1  = (const float*)d_in[1];
  // d_in[2]=b1, d_in[6]=b2 cancel inside the train-mode batchnorms
  const float* g1  = (const float*)d_in[3];
  const float* be1 = (const float*)d_in[4];
  const float* W2  = (const float*)d_in[5];
  const float* g2  = (const float*)d_in[7];
  const float* be2 = (const float*)d_in[8];
  const float* Wfc = (const float*)d_in[9];
  const float* bfc = (const float*)d_in[10];
  float* out = (float*)d_out;

  char* ws = (char*)d_ws;
  unsigned short* wb = (unsigned short*)ws;                 // 2 MB swizzled bf16 Wfc
  float* pt     = (float*)(ws + (2u << 20));                // 208 KB [d][52] params
  float* shared = (float*)(ws + (2u << 20) + (256u << 10)); // 2 MB reused partials
  float* ps1  = shared;                                     // 256 x 2048 (stats1)
  float* ps2s = shared;                                     // 32 x 4096 (stats2 sum)
  float* ps2q = shared + 32 * 4096;                         // 32 x 4096 (stats2 sq)

  const size_t PART_OFF = (2u << 20) + (256u << 10) + (2u << 20);  // 4,456,448
  const size_t PART_SZ  = (size_t)4 * 8192 * 256 * sizeof(float);  // 32 MB
  float* part = (float*)(ws + PART_OFF);
  const int use_part = (ws_size >= PART_OFF + PART_SZ) ? 1 : 0;

  if (!use_part)
    hipMemsetAsync(d_out, 0, (size_t)out_size * sizeof(float), stream);

  k_pre   <<<dim3(768),    256, 0, stream>>>(Wfc, wb, x, ps1);
  k_fin1  <<<dim3(32),     256, 0, stream>>>(ps1, W1, g1, be1, pt);
  k_stats2<<<dim3(32, 32), 256, 0, stream>>>(x, pt, W2, ps2s, ps2q);
  k_fin2  <<<dim3(16),     256, 0, stream>>>(W2, g2, be2, ps2s, ps2q, pt);
  k_gemm  <<<dim3(128, 4), 256, 0, stream>>>(x, pt, wb, bfc, out, part, use_part);
  if (use_part)
    k_merge<<<dim3(2048),  256, 0, stream>>>(part, bfc, out);
}